// Round 3
// baseline (64511.237 us; speedup 1.0000x reference)
//
#include <hip/hip_runtime.h>
#include <hip/hip_bf16.h>

typedef __attribute__((ext_vector_type(8))) short bf16x8;
typedef __attribute__((ext_vector_type(4))) float f32x4;
typedef __attribute__((ext_vector_type(4))) float fvec4;
typedef __attribute__((ext_vector_type(4))) unsigned short u16x4;

#define DEVI __device__ __forceinline__

constexpr int BB = 256, TT = 1024, FF = 128, HH = 512, OO = 64;
constexpr int KK = 256;    // fused input width [x_imp | m]
constexpr int NN = 2048;   // fused gate width  [z | r | htilde | gamma_h]

DEVI unsigned short f2bf(float x) {
  unsigned int u = __float_as_uint(x);
  u += 0x7FFFu + ((u >> 16) & 1u);          // RNE
  return (unsigned short)(u >> 16);
}
DEVI float bf2f(unsigned short s) {
  return __uint_as_float(((unsigned int)s) << 16);
}

// ---------------------------------------------------------------------------
// K0: pack weights + init sync flags.
//   BwT [2048][256] bf16 : row n = column n of fused K x N weight.
//   bias[2048] f32 : b_* + colsum(V_*)  (gamma rows: b_gamma_h)
//   Uzr [64 tiles][16 kt][64 lane][8] bf16 (tiles 0..31 U_z cols, 32..63 U_r)
//   Upk [32 tiles][16 kt][64 lane][8] bf16 (U)
//   frag value (tile,kt,l,j) = U[kt*32 + (l>>4)*8 + j][tile*16 + (l&15)]
// ---------------------------------------------------------------------------
__global__ __launch_bounds__(256) void prep_kernel(
    const float* __restrict__ W_z, const float* __restrict__ V_z, const float* __restrict__ b_z,
    const float* __restrict__ W_r, const float* __restrict__ V_r, const float* __restrict__ b_r,
    const float* __restrict__ Wh,  const float* __restrict__ Vh,  const float* __restrict__ bh,
    const float* __restrict__ Wgh, const float* __restrict__ bgh,
    const float* __restrict__ U_z, const float* __restrict__ U_r, const float* __restrict__ Uh,
    unsigned short* __restrict__ BwT, float* __restrict__ bias,
    unsigned short* __restrict__ Uzr, unsigned short* __restrict__ Upk,
    int* __restrict__ hdFlag, int* __restrict__ a2Flag)
{
  int idx = blockIdx.x * 256 + threadIdx.x;
  if (idx < 524288) {                       // BwT
    int n = idx >> 8, k = idx & 255;
    float v;
    if (n < 512)       { int h = n;        v = (k < 128) ? W_z[k*HH + h] : -V_z[(k-128)*HH + h]; }
    else if (n < 1024) { int h = n - 512;  v = (k < 128) ? W_r[k*HH + h] : -V_r[(k-128)*HH + h]; }
    else if (n < 1536) { int h = n - 1024; v = (k < 128) ? Wh [k*HH + h] : -Vh [(k-128)*HH + h]; }
    else               { int h = n - 1536; v = (k < 128) ? 0.f : Wgh[(k-128)*HH + h]; }
    BwT[n*256 + k] = f2bf(v);
    return;
  }
  idx -= 524288;
  if (idx < 2048) {                         // bias
    int n = idx; float v;
    if (n < 512)       { float s = b_z[n];      for (int f = 0; f < FF; ++f) s += V_z[f*HH + n];        v = s; }
    else if (n < 1024) { int h = n-512;  float s = b_r[h]; for (int f = 0; f < FF; ++f) s += V_r[f*HH + h]; v = s; }
    else if (n < 1536) { int h = n-1024; float s = bh[h];  for (int f = 0; f < FF; ++f) s += Vh[f*HH + h];  v = s; }
    else               { v = bgh[n-1536]; }
    bias[n] = v;
    return;
  }
  idx -= 2048;
  if (idx < 524288) {                       // Uzr pack
    int j = idx & 7, l = (idx >> 3) & 63, kt = (idx >> 9) & 15, tile = idx >> 13;
    int k = kt*32 + (l >> 4)*8 + j;
    int col = ((tile < 32) ? tile : tile - 32)*16 + (l & 15);
    float v = (tile < 32) ? U_z[k*HH + col] : U_r[k*HH + col];
    Uzr[idx] = f2bf(v);
    return;
  }
  idx -= 524288;
  if (idx < 262144) {                       // U pack
    int j = idx & 7, l = (idx >> 3) & 63, kt = (idx >> 9) & 15, tile = idx >> 13;
    int k = kt*32 + (l >> 4)*8 + j;
    int col = tile*16 + (l & 15);
    Upk[idx] = f2bf(Uh[k*HH + col]);
    return;
  }
  idx -= 262144;
  if (idx < 256) { hdFlag[idx] = 0; return; }   // flag init (per replay)
  idx -= 256;
  if (idx < 256) { a2Flag[idx] = 0; return; }
}

// ---------------------------------------------------------------------------
// K1: imputation + fused A chunk [B*TC][256] bf16 = [x_imp | m]
// ---------------------------------------------------------------------------
__global__ __launch_bounds__(256) void build_A_kernel(
    const float* __restrict__ x, const float* __restrict__ delta,
    const float* __restrict__ mm, const float* __restrict__ xf,
    const float* __restrict__ Wgx, const float* __restrict__ bgx,
    const int* __restrict__ bs, unsigned short* __restrict__ A,
    int t0, int TC)
{
  int blk = blockIdx.x;
  int row8 = blk * 8;
  int b0  = row8 / TC;
  int tl0 = row8 % TC;
  if (b0 >= bs[t0 + tl0]) return;
  int tid = threadIdx.x;
  int rl = row8 + (tid >> 5);
  int tc = tl0 + (tid >> 5);
  long gi = ((long)b0*TT + t0 + tc) * 32 + (tid & 31);
  int f0 = (tid & 31) * 4;
  fvec4 xv = ((const fvec4*)x)[gi];
  fvec4 dv = ((const fvec4*)delta)[gi];
  fvec4 mv = ((const fvec4*)mm)[gi];
  fvec4 fv = ((const fvec4*)xf)[gi];
  unsigned short ox[4], om[4];
#pragma unroll
  for (int j = 0; j < 4; ++j) {
    float g  = __expf(-fmaxf(dv[j]*Wgx[f0+j] + bgx[f0+j], 0.f));
    float xr = g*fv[j] + (1.f - g)*0.001f;
    float xi = (mv[j] > 0.5f) ? xr : xv[j];
    ox[j] = f2bf(xi); om[j] = f2bf(mv[j]);
  }
  *(u16x4*)(A + (long)rl*KK + f0)       = (u16x4){ox[0], ox[1], ox[2], ox[3]};
  *(u16x4*)(A + (long)rl*KK + 128 + f0) = (u16x4){om[0], om[1], om[2], om[3]};
}

// ---------------------------------------------------------------------------
// K2: chunk GEMM  PRE[m][n] = A[m][:] @ Bw[:,n] + bias[n]  (bf16 MFMA, K=256)
// ---------------------------------------------------------------------------
__global__ __launch_bounds__(256) void gemm1_kernel(
    const unsigned short* __restrict__ A, const unsigned short* __restrict__ BwT,
    const float* __restrict__ bias, const int* __restrict__ bs,
    unsigned short* __restrict__ PRE, int t0, int TC)
{
  int blk = blockIdx.x;
  int nt = blk & 15;
  int mt = blk >> 4;
  {
    int m0 = mt * 128;
    int b_ = m0 / TC;
    int bcheck = (TC >= 128) ? bs[t0 + (m0 % TC)] : bs[t0];
    if (b_ >= bcheck) return;
  }
  int tid = threadIdx.x;
  int w = tid >> 6, l = tid & 63;
  int wm = w >> 1, wn = w & 1;
  int lr = l & 15, lg = l >> 4;
  int m_base = mt*128 + wm*64;
  int n_base = nt*128 + wn*64;
  const unsigned short* Aptr = A   + (long)(m_base + lr)*KK + lg*8;
  const unsigned short* Bptr = BwT + (long)(n_base + lr)*KK + lg*8;
  f32x4 acc[4][4];
#pragma unroll
  for (int i = 0; i < 4; ++i)
#pragma unroll
    for (int j = 0; j < 4; ++j) acc[i][j] = (f32x4){0.f, 0.f, 0.f, 0.f};

#pragma unroll
  for (int kt = 0; kt < 8; ++kt) {
    bf16x8 af[4], bfr[4];
#pragma unroll
    for (int i = 0; i < 4; ++i) af[i]  = *(const bf16x8*)(Aptr + (long)i*16*KK + kt*32);
#pragma unroll
    for (int i = 0; i < 4; ++i) bfr[i] = *(const bf16x8*)(Bptr + (long)i*16*KK + kt*32);
#pragma unroll
    for (int ms = 0; ms < 4; ++ms)
#pragma unroll
      for (int ns = 0; ns < 4; ++ns)
        acc[ms][ns] = __builtin_amdgcn_mfma_f32_16x16x32_bf16(af[ms], bfr[ns], acc[ms][ns], 0, 0, 0);
  }
#pragma unroll
  for (int ms = 0; ms < 4; ++ms) {
    int gm0 = m_base + ms*16 + lg*4;
#pragma unroll
    for (int ns = 0; ns < 4; ++ns) {
      int gn = n_base + ns*16 + lr;
      float bv = bias[gn];
      bool is_gamma = (gn >= 1536);
#pragma unroll
      for (int q = 0; q < 4; ++q) {
        float v = acc[ms][ns][q] + bv;
        if (is_gamma) v = __expf(-fmaxf(v, 0.f));
        PRE[(long)(gm0 + q)*NN + gn] = f2bf(v);
      }
    }
  }
}

// ---------------------------------------------------------------------------
// K3: cluster-parallel scan. 16 clusters x 16 blocks (256 blocks, 1/CU).
//   Cluster cl = blockIdx&15 owns rows [16cl,16cl+16); member g = blockIdx>>4
//   owns H-cols [32g,32g+32) of z, r, h~, h. U slices live in LDS all chunk.
//   Per step: exchange hd frags and (hd*r) frags (MFMA A-layout, kt=owner)
//   via L2 scratch + per-producer monotone step flags (release/acquire).
//   Double-buffered by t&1 (writer provably <=1 step ahead of readers).
// ---------------------------------------------------------------------------
__global__ __launch_bounds__(256) void scan_kernel(
    const unsigned short* __restrict__ PRE,
    const unsigned short* __restrict__ Uzr,
    const unsigned short* __restrict__ Upk,
    const int* __restrict__ bs,
    float* __restrict__ h_st,
    unsigned short* __restrict__ hdF,
    unsigned short* __restrict__ a2F,
    int* __restrict__ hdFlag,
    int* __restrict__ a2Flag,
    int t0, int TC)
{
  const int tid = threadIdx.x;
  const int cl  = blockIdx.x & 15;
  const int g   = blockIdx.x >> 4;
  const int r0  = cl * 16;
  if (t0 > 0 && bs[t0] <= r0) return;     // cluster retired in earlier chunk

  __shared__ __align__(16) unsigned short Uz_l[2*16*64*8];   // 32 KB
  __shared__ __align__(16) unsigned short Ur_l[2*16*64*8];   // 32 KB
  __shared__ __align__(16) unsigned short Uh_l[2*16*64*8];   // 32 KB
  __shared__ __align__(16) unsigned short hd_l[16*64*8];     // 16 KB (hd, then a2)
  __shared__ __align__(16) unsigned short slab[2][4][16][32];// 8 KB  (z|r|h|gam pre)
  __shared__ float hm[16][33];                               // 2.1 KB h master
  __shared__ unsigned short rbuf[16][40];                    // 1.3 KB r exchange

  // load U slices: z tiles {2g,2g+1}, r tiles {32+2g,+1}, h~ tiles {2g,+1}
  {
    const unsigned short* srcZ = Uzr + (size_t)(2*g)*8192;
    const unsigned short* srcR = Uzr + (size_t)(32 + 2*g)*8192;
    const unsigned short* srcH = Upk + (size_t)(2*g)*8192;
    for (int s = tid*8; s < 16384; s += 256*8) {
      *(bf16x8*)&Uz_l[s] = *(const bf16x8*)&srcZ[s];
      *(bf16x8*)&Ur_l[s] = *(const bf16x8*)&srcR[s];
      *(bf16x8*)&Uh_l[s] = *(const bf16x8*)&srcH[s];
    }
  }
  if (t0 == 0) {
    for (int i = tid; i < 16*32; i += 256) hm[i>>5][i&31] = 0.f;
  } else {
    for (int i = tid; i < 16*32; i += 256)
      hm[i>>5][i&31] = h_st[(size_t)(r0 + (i>>5))*HH + 32*g + (i&31)];
  }

  const int w  = tid >> 6;
  const int l  = tid & 63;
  const int lr = l & 15;
  const int lg = l >> 4;
  float zreg[4];

  int tc = 0;
  for (; tc < TC; ++tc) {
    const int tabs = t0 + tc;
    const int bsv  = bs[tabs];
    if (bsv <= r0) break;                  // descending bs: cluster done forever
    const int na  = min(16, bsv - r0);
    const int buf = tc & 1;

    // (1) stage PRE slab for step t: 4 gates x 16 rows x 32 cols
    {
      int gate = tid >> 6, row = (tid >> 2) & 15, seg = tid & 3;
      const unsigned short* src = PRE + ((size_t)(r0+row)*TC + tc)*NN
                                      + gate*512 + g*32 + seg*8;
      bf16x8 v = *(const bf16x8*)src;
      *(bf16x8*)&slab[buf][gate][row][seg*8] = v;
    }
    __syncthreads();                       // S1: slab ready; prev hm writes done

    // (2) wave 0: build + publish hd(t) own slice (A-frag layout, kt = g)
    if (w == 0) {
      unsigned short hdv[8];
#pragma unroll
      for (int j = 0; j < 8; ++j) {
        int kl = lg*8 + j;
        float h  = hm[lr][kl];
        float gv = bf2f(slab[buf][3][lr][kl]);
        hdv[j] = f2bf(lr < na ? gv*h : h);
      }
      size_t o = (((size_t)(cl*2+buf)*16 + g)*64 + l)*8;
      *(u16x4*)&hdF[o]     = *(u16x4*)&hdv[0];
      *(u16x4*)&hdF[o + 4] = *(u16x4*)&hdv[4];
      __threadfence();
      if (tid == 0)
        __hip_atomic_store(&hdFlag[cl*16+g], tabs+1, __ATOMIC_RELEASE, __HIP_MEMORY_SCOPE_AGENT);
    }
    // spin: all 16 hd slices ready
    if (l < 16) {
      long guard = 0;
      while (__hip_atomic_load(&hdFlag[cl*16+l], __ATOMIC_ACQUIRE, __HIP_MEMORY_SCOPE_AGENT) < tabs+1) {
        __builtin_amdgcn_s_sleep(2);
        if (++guard > (1L<<26)) break;     // bail visibly instead of hanging
      }
    }
    __threadfence();
    // (3) stage hd -> LDS (16 KB)
    {
      const unsigned short* src = hdF + (size_t)(cl*2+buf)*8192;
#pragma unroll
      for (int c = 0; c < 4; ++c) {
        int s = tid*32 + c*8;
        *(bf16x8*)&hd_l[s] = *(const bf16x8*)&src[s];
      }
    }
    __syncthreads();                       // S2

    // (4) phase A: z (waves 0,1), r (waves 2,3); wave tile tl = w&1
    {
      const unsigned short* Ub = (w < 2) ? Uz_l : Ur_l;
      const int tl = w & 1;
      f32x4 acc = {0.f,0.f,0.f,0.f};
#pragma unroll
      for (int kt = 0; kt < 16; ++kt) {
        bf16x8 af = *(const bf16x8*)&hd_l[(kt*64 + l)*8];
        bf16x8 bf = *(const bf16x8*)&Ub[((tl*16 + kt)*64 + l)*8];
        acc = __builtin_amdgcn_mfma_f32_16x16x32_bf16(af, bf, acc, 0, 0, 0);
      }
      if (w < 2) {
#pragma unroll
        for (int q = 0; q < 4; ++q) {
          int row = lg*4 + q;
          float p = bf2f(slab[buf][0][row][tl*16 + lr]);
          zreg[q] = 1.f/(1.f + __expf(-(p + acc[q])));
        }
      } else {
#pragma unroll
        for (int q = 0; q < 4; ++q) {
          int row = lg*4 + q;
          float p = bf2f(slab[buf][1][row][tl*16 + lr]);
          rbuf[row][tl*16 + lr] = f2bf(1.f/(1.f + __expf(-(p + acc[q]))));
        }
      }
    }
    __syncthreads();                       // S3: rbuf complete

    // (5) wave 3: build + publish a2(t) = hd*r own slice (kt = g)
    if (w == 3) {
      unsigned short a2v[8];
#pragma unroll
      for (int j = 0; j < 8; ++j) {
        int kl = lg*8 + j;
        a2v[j] = f2bf(bf2f(rbuf[lr][kl]) * bf2f(hd_l[(g*64 + l)*8 + j]));
      }
      size_t o = (((size_t)(cl*2+buf)*16 + g)*64 + l)*8;
      *(u16x4*)&a2F[o]     = *(u16x4*)&a2v[0];
      *(u16x4*)&a2F[o + 4] = *(u16x4*)&a2v[4];
      __threadfence();
      if (l == 0)
        __hip_atomic_store(&a2Flag[cl*16+g], tabs+1, __ATOMIC_RELEASE, __HIP_MEMORY_SCOPE_AGENT);
    }
    if (l < 16) {
      long guard = 0;
      while (__hip_atomic_load(&a2Flag[cl*16+l], __ATOMIC_ACQUIRE, __HIP_MEMORY_SCOPE_AGENT) < tabs+1) {
        __builtin_amdgcn_s_sleep(2);
        if (++guard > (1L<<26)) break;
      }
    }
    __threadfence();
    // (6) stage a2 -> hd_l (safe: own a2 flag implies wave-3 reads done; S3
    //     implies all phase-A hd_l reads done)
    {
      const unsigned short* src = a2F + (size_t)(cl*2+buf)*8192;
#pragma unroll
      for (int c = 0; c < 4; ++c) {
        int s = tid*32 + c*8;
        *(bf16x8*)&hd_l[s] = *(const bf16x8*)&src[s];
      }
    }
    __syncthreads();                       // S4

    // (7) phase B: h~ + h update (waves 0,1 own tile w; z regs align)
    if (w < 2) {
      const int tl = w;
      f32x4 acc = {0.f,0.f,0.f,0.f};
#pragma unroll
      for (int kt = 0; kt < 16; ++kt) {
        bf16x8 af = *(const bf16x8*)&hd_l[(kt*64 + l)*8];
        bf16x8 bf = *(const bf16x8*)&Uh_l[((tl*16 + kt)*64 + l)*8];
        acc = __builtin_amdgcn_mfma_f32_16x16x32_bf16(af, bf, acc, 0, 0, 0);
      }
#pragma unroll
      for (int q = 0; q < 4; ++q) {
        int row = lg*4 + q;
        if (row < na) {
          int col = tl*16 + lr;
          float ph = bf2f(slab[buf][2][row][col]);
          float e  = __expf(2.f*(ph + acc[q]));
          float th = 1.f - 2.f/(e + 1.f);           // tanh, overflow-safe
          float gv = bf2f(slab[buf][3][row][col]);
          float hv = hm[row][col];
          float hd = gv * hv;
          hm[row][col] = hd + zreg[q]*(th - hd);
        }
      }
    }
    // next-iter S1 orders hm writes before the next hd build
  }
  __syncthreads();
  for (int i = tid; i < 16*32; i += 256)
    h_st[(size_t)(r0 + (i>>5))*HH + 32*g + (i&31)] = hm[i>>5][i&31];
}

// ---------------------------------------------------------------------------
// K4: head: eval BatchNorm + decoder GEMV + log_softmax.
//   d_out = [output (256x64) | h_bn (256x512)] fp32
// ---------------------------------------------------------------------------
__global__ __launch_bounds__(64) void head_kernel(
    const float* __restrict__ h_state, const float* __restrict__ decW,
    const float* __restrict__ decb, const float* __restrict__ bnw,
    const float* __restrict__ bnb, float* __restrict__ out)
{
  int b = blockIdx.x, o = threadIdx.x;
  __shared__ float hbn[HH];
  const float s = rsqrtf(1.f + 1e-5f);
  for (int j = o; j < HH; j += 64)
    hbn[j] = h_state[(long)b*HH + j] * (bnw[j] * s) + bnb[j];
  __syncthreads();
  float acc = decb[o];
  for (int j = 0; j < HH; ++j) acc += hbn[j] * decW[j*OO + o];
  float mx = acc;
#pragma unroll
  for (int off = 32; off > 0; off >>= 1) mx = fmaxf(mx, __shfl_xor(mx, off));
  float ex = __expf(acc - mx);
  float sum = ex;
#pragma unroll
  for (int off = 32; off > 0; off >>= 1) sum += __shfl_xor(sum, off);
  out[(long)b*OO + o] = acc - mx - __logf(sum);
  for (int j = o; j < HH; j += 64)
    out[(long)BB*OO + (long)b*HH + j] = hbn[j];
}

// ---------------------------------------------------------------------------
extern "C" void kernel_launch(void* const* d_in, const int* in_sizes, int n_in,
                              void* d_out, int out_size, void* d_ws, size_t ws_size,
                              hipStream_t stream) {
  const float* x     = (const float*)d_in[0];
  const float* delta = (const float*)d_in[1];
  const float* mm    = (const float*)d_in[2];
  const float* xf    = (const float*)d_in[3];
  const int*   bs    = (const int*)  d_in[4];
  const float* W_r   = (const float*)d_in[5];
  const float* U_r   = (const float*)d_in[6];
  const float* V_r   = (const float*)d_in[7];
  const float* b_r   = (const float*)d_in[8];
  const float* W_z   = (const float*)d_in[9];
  const float* U_z   = (const float*)d_in[10];
  const float* V_z   = (const float*)d_in[11];
  const float* b_z   = (const float*)d_in[12];
  const float* W     = (const float*)d_in[13];
  const float* U     = (const float*)d_in[14];
  const float* V     = (const float*)d_in[15];
  const float* b     = (const float*)d_in[16];
  const float* Wgx   = (const float*)d_in[17];
  const float* bgx   = (const float*)d_in[18];
  const float* Wgh   = (const float*)d_in[19];
  const float* bgh   = (const float*)d_in[20];
  const float* decW  = (const float*)d_in[21];
  const float* decb  = (const float*)d_in[22];
  const float* bnw   = (const float*)d_in[23];
  const float* bnb   = (const float*)d_in[24];

  auto rnd = [](size_t v) { return (v + 255) & ~(size_t)255; };
  const size_t fixed_bytes = rnd((size_t)2048*256*2) + rnd(2048*4)
                           + rnd((size_t)64*16*64*8*2) + rnd((size_t)32*16*64*8*2)
                           + rnd((size_t)BB*HH*4)
                           + 2*rnd((size_t)16*2*16*64*8*2)   // hdF, a2F
                           + 2*rnd((size_t)256*4);           // flags
  int TC = 0;
  const int cands[5] = {128, 64, 32, 16, 8};
  for (int i = 0; i < 5; ++i) {
    size_t need = fixed_bytes + rnd((size_t)BB*cands[i]*KK*2) + rnd((size_t)BB*cands[i]*NN*2);
    if (need <= ws_size) { TC = cands[i]; break; }
  }
  if (TC == 0) return;

  char* p = (char*)d_ws;
  auto alloc = [&](size_t bytes) { char* r = p; p += (bytes + 255) & ~(size_t)255; return r; };
  unsigned short* A_chunk = (unsigned short*)alloc((size_t)BB * TC * KK * 2);
  unsigned short* PREc    = (unsigned short*)alloc((size_t)BB * TC * NN * 2);
  unsigned short* BwT     = (unsigned short*)alloc((size_t)2048 * 256 * 2);
  float*          bias    = (float*)alloc(2048 * 4);
  unsigned short* Uzr     = (unsigned short*)alloc((size_t)64*16*64*8 * 2);
  unsigned short* Upk     = (unsigned short*)alloc((size_t)32*16*64*8 * 2);
  float*          h_st    = (float*)alloc((size_t)BB * HH * 4);
  unsigned short* hdF     = (unsigned short*)alloc((size_t)16*2*16*64*8 * 2);
  unsigned short* a2F     = (unsigned short*)alloc((size_t)16*2*16*64*8 * 2);
  int*            hdFlag  = (int*)alloc(256 * 4);
  int*            a2Flag  = (int*)alloc(256 * 4);

  prep_kernel<<<5130, 256, 0, stream>>>(W_z, V_z, b_z, W_r, V_r, b_r, W, V, b,
                                        Wgh, bgh, U_z, U_r, U, BwT, bias, Uzr, Upk,
                                        hdFlag, a2Flag);
  const int nch = TT / TC;
  for (int c = 0; c < nch; ++c) {
    int t0v = c * TC, TCv = TC;
    build_A_kernel<<<BB*TC/8, 256, 0, stream>>>(x, delta, mm, xf, Wgx, bgx, bs,
                                                A_chunk, t0v, TCv);
    gemm1_kernel<<<(BB*TC/128)*16, 256, 0, stream>>>(A_chunk, BwT, bias, bs,
                                                     PREc, t0v, TCv);
    const unsigned short* PREcc = PREc;
    const unsigned short* Uzrc  = Uzr;
    const unsigned short* Upkc  = Upk;
    const int* bsc = bs;
    void* sargs[] = {(void*)&PREcc, (void*)&Uzrc, (void*)&Upkc, (void*)&bsc,
                     (void*)&h_st, (void*)&hdF, (void*)&a2F,
                     (void*)&hdFlag, (void*)&a2Flag, (void*)&t0v, (void*)&TCv};
    hipLaunchCooperativeKernel((const void*)scan_kernel, dim3(256), dim3(256),
                               sargs, 0, stream);
  }
  head_kernel<<<256, 64, 0, stream>>>(h_st, decW, decb, bnw, bnb, (float*)d_out);
}

// Round 4
// 39405.884 us; speedup vs baseline: 1.6371x; 1.6371x over previous
//
#include <hip/hip_runtime.h>
#include <hip/hip_bf16.h>

typedef __attribute__((ext_vector_type(8))) short bf16x8;
typedef __attribute__((ext_vector_type(4))) float f32x4;
typedef __attribute__((ext_vector_type(4))) float fvec4;
typedef __attribute__((ext_vector_type(4))) unsigned short u16x4;

#define DEVI __device__ __forceinline__

constexpr int BB = 256, TT = 1024, FF = 128, HH = 512, OO = 64;
constexpr int KK = 256;    // fused input width [x_imp | m]
constexpr int NN = 2048;   // fused gate width  [z | r | htilde | gamma_h]

DEVI unsigned short f2bf(float x) {
  unsigned int u = __float_as_uint(x);
  u += 0x7FFFu + ((u >> 16) & 1u);          // RNE
  return (unsigned short)(u >> 16);
}
DEVI float bf2f(unsigned short s) {
  return __uint_as_float(((unsigned int)s) << 16);
}

// async global->LDS, 16B per lane; LDS dest = uniform base + lane*16
DEVI void gload16(const unsigned short* g, unsigned short* lds) {
  __builtin_amdgcn_global_load_lds(
      (const __attribute__((address_space(1))) void*)g,
      (__attribute__((address_space(3))) void*)lds, 16, 0, 0);
}

DEVI void barrier_lds() {       // raw barrier: waits LDS ops only, vmcnt SURVIVES
  asm volatile("s_waitcnt lgkmcnt(0)" ::: "memory");
  __builtin_amdgcn_s_barrier();
  __builtin_amdgcn_sched_barrier(0);
}

// ---------------------------------------------------------------------------
// K0: pack weights.
//   BwT [2048][256] bf16 : row n = column n of fused K x N weight.
//   bias[2048] f32 : b_* + colsum(V_*)  (gamma rows: b_gamma_h)
//   UzrP [16 kt][64 nt][64 l][8] bf16 : nt<32 -> U_z cols, nt>=32 -> U_r cols
//   UhP  [16 kt][32 nt][64 l][8] bf16 : U
//   frag value (kt,nt,l,j) = U[kt*32 + (l>>4)*8 + j][(nt&31)*16 + (l&15)]
// ---------------------------------------------------------------------------
__global__ __launch_bounds__(256) void prep_kernel(
    const float* __restrict__ W_z, const float* __restrict__ V_z, const float* __restrict__ b_z,
    const float* __restrict__ W_r, const float* __restrict__ V_r, const float* __restrict__ b_r,
    const float* __restrict__ Wh,  const float* __restrict__ Vh,  const float* __restrict__ bh,
    const float* __restrict__ Wgh, const float* __restrict__ bgh,
    const float* __restrict__ U_z, const float* __restrict__ U_r, const float* __restrict__ Uh,
    unsigned short* __restrict__ BwT, float* __restrict__ bias,
    unsigned short* __restrict__ UzrP, unsigned short* __restrict__ UhP)
{
  int idx = blockIdx.x * 256 + threadIdx.x;
  if (idx < 524288) {                       // BwT
    int n = idx >> 8, k = idx & 255;
    float v;
    if (n < 512)       { int h = n;        v = (k < 128) ? W_z[k*HH + h] : -V_z[(k-128)*HH + h]; }
    else if (n < 1024) { int h = n - 512;  v = (k < 128) ? W_r[k*HH + h] : -V_r[(k-128)*HH + h]; }
    else if (n < 1536) { int h = n - 1024; v = (k < 128) ? Wh [k*HH + h] : -Vh [(k-128)*HH + h]; }
    else               { int h = n - 1536; v = (k < 128) ? 0.f : Wgh[(k-128)*HH + h]; }
    BwT[n*256 + k] = f2bf(v);
    return;
  }
  idx -= 524288;
  if (idx < 2048) {                         // bias
    int n = idx; float v;
    if (n < 512)       { float s = b_z[n];      for (int f = 0; f < FF; ++f) s += V_z[f*HH + n];        v = s; }
    else if (n < 1024) { int h = n-512;  float s = b_r[h]; for (int f = 0; f < FF; ++f) s += V_r[f*HH + h]; v = s; }
    else if (n < 1536) { int h = n-1024; float s = bh[h];  for (int f = 0; f < FF; ++f) s += Vh[f*HH + h];  v = s; }
    else               { v = bgh[n-1536]; }
    bias[n] = v;
    return;
  }
  idx -= 2048;
  if (idx < 524288) {                       // UzrP pack (kt-major)
    int j = idx & 7, l = (idx >> 3) & 63, nt = (idx >> 9) & 63, kt = idx >> 15;
    int k = kt*32 + (l >> 4)*8 + j;
    int col = (nt & 31)*16 + (l & 15);
    float v = (nt < 32) ? U_z[k*HH + col] : U_r[k*HH + col];
    UzrP[idx] = f2bf(v);
    return;
  }
  idx -= 524288;
  if (idx < 262144) {                       // UhP pack (kt-major)
    int j = idx & 7, l = (idx >> 3) & 63, nt = (idx >> 9) & 31, kt = idx >> 14;
    int k = kt*32 + (l >> 4)*8 + j;
    UhP[idx] = f2bf(Uh[k*HH + nt*16 + (l & 15)]);
  }
}

// ---------------------------------------------------------------------------
// K1: imputation + fused A chunk [B*TC][256] bf16 = [x_imp | m]
// ---------------------------------------------------------------------------
__global__ __launch_bounds__(256) void build_A_kernel(
    const float* __restrict__ x, const float* __restrict__ delta,
    const float* __restrict__ mm, const float* __restrict__ xf,
    const float* __restrict__ Wgx, const float* __restrict__ bgx,
    const int* __restrict__ bs, unsigned short* __restrict__ A,
    int t0, int TC)
{
  int blk = blockIdx.x;
  int row8 = blk * 8;
  int b0  = row8 / TC;
  int tl0 = row8 % TC;
  if (b0 >= bs[t0 + tl0]) return;
  int tid = threadIdx.x;
  int rl = row8 + (tid >> 5);
  int tc = tl0 + (tid >> 5);
  long gi = ((long)b0*TT + t0 + tc) * 32 + (tid & 31);
  int f0 = (tid & 31) * 4;
  fvec4 xv = ((const fvec4*)x)[gi];
  fvec4 dv = ((const fvec4*)delta)[gi];
  fvec4 mv = ((const fvec4*)mm)[gi];
  fvec4 fv = ((const fvec4*)xf)[gi];
  unsigned short ox[4], om[4];
#pragma unroll
  for (int j = 0; j < 4; ++j) {
    float g  = __expf(-fmaxf(dv[j]*Wgx[f0+j] + bgx[f0+j], 0.f));
    float xr = g*fv[j] + (1.f - g)*0.001f;
    float xi = (mv[j] > 0.5f) ? xr : xv[j];
    ox[j] = f2bf(xi); om[j] = f2bf(mv[j]);
  }
  *(u16x4*)(A + (long)rl*KK + f0)       = (u16x4){ox[0], ox[1], ox[2], ox[3]};
  *(u16x4*)(A + (long)rl*KK + 128 + f0) = (u16x4){om[0], om[1], om[2], om[3]};
}

// ---------------------------------------------------------------------------
// K2: chunk GEMM  PRE[m][n] = A[m][:] @ Bw[:,n] + bias[n]  (bf16 MFMA, K=256)
// ---------------------------------------------------------------------------
__global__ __launch_bounds__(256) void gemm1_kernel(
    const unsigned short* __restrict__ A, const unsigned short* __restrict__ BwT,
    const float* __restrict__ bias, const int* __restrict__ bs,
    unsigned short* __restrict__ PRE, int t0, int TC)
{
  int blk = blockIdx.x;
  int nt = blk & 15;
  int mt = blk >> 4;
  {
    int m0 = mt * 128;
    int b_ = m0 / TC;
    int bcheck = (TC >= 128) ? bs[t0 + (m0 % TC)] : bs[t0];
    if (b_ >= bcheck) return;
  }
  int tid = threadIdx.x;
  int w = tid >> 6, l = tid & 63;
  int wm = w >> 1, wn = w & 1;
  int lr = l & 15, lg = l >> 4;
  int m_base = mt*128 + wm*64;
  int n_base = nt*128 + wn*64;
  const unsigned short* Aptr = A   + (long)(m_base + lr)*KK + lg*8;
  const unsigned short* Bptr = BwT + (long)(n_base + lr)*KK + lg*8;
  f32x4 acc[4][4];
#pragma unroll
  for (int i = 0; i < 4; ++i)
#pragma unroll
    for (int j = 0; j < 4; ++j) acc[i][j] = (f32x4){0.f, 0.f, 0.f, 0.f};

#pragma unroll
  for (int kt = 0; kt < 8; ++kt) {
    bf16x8 af[4], bfr[4];
#pragma unroll
    for (int i = 0; i < 4; ++i) af[i]  = *(const bf16x8*)(Aptr + (long)i*16*KK + kt*32);
#pragma unroll
    for (int i = 0; i < 4; ++i) bfr[i] = *(const bf16x8*)(Bptr + (long)i*16*KK + kt*32);
#pragma unroll
    for (int ms = 0; ms < 4; ++ms)
#pragma unroll
      for (int ns = 0; ns < 4; ++ns)
        acc[ms][ns] = __builtin_amdgcn_mfma_f32_16x16x32_bf16(af[ms], bfr[ns], acc[ms][ns], 0, 0, 0);
  }
#pragma unroll
  for (int ms = 0; ms < 4; ++ms) {
    int gm0 = m_base + ms*16 + lg*4;
#pragma unroll
    for (int ns = 0; ns < 4; ++ns) {
      int gn = n_base + ns*16 + lr;
      float bv = bias[gn];
      bool is_gamma = (gn >= 1536);
#pragma unroll
      for (int q = 0; q < 4; ++q) {
        float v = acc[ms][ns][q] + bv;
        if (is_gamma) v = __expf(-fmaxf(v, 0.f));
        PRE[(long)(gm0 + q)*NN + gn] = f2bf(v);
      }
    }
  }
}

// ---------------------------------------------------------------------------
// K3: sequential scan, 16 independent blocks x 512 threads (8 waves).
//   Block j owns batch rows [16j,16j+16). Per step, each wave streams the U
//   tiles IT consumes via global_load_lds into a PRIVATE LDS double buffer:
//   one continuous unit stream (32 zr-units + 16 h-units per step), stage
//   unit u+2 at consume u, counted s_waitcnt vmcnt(4) (own 4 loads oldest).
//   Cross-wave handoffs (hd frags, r, hm) use raw s_barrier + lgkmcnt(0)
//   only -> the vm pipeline survives barriers and step boundaries.
// ---------------------------------------------------------------------------
__global__ __launch_bounds__(512) void scan_kernel(
    const unsigned short* __restrict__ PRE,
    const unsigned short* __restrict__ UzrP,
    const unsigned short* __restrict__ UhP,
    const int* __restrict__ bs,
    float* __restrict__ h_st,
    int t0, int TC)
{
  __shared__ __align__(16) unsigned short Ubuf[8][2][2048];  // 64 KB (per-wave dbuf)
  __shared__ __align__(16) unsigned short hd_l[8192];        // 16 KB (hd, then hd*r)
  __shared__ float hm[16][520];                              // 33.3 KB (h master f32)
  __shared__ unsigned short rbuf[16][520];                   // 16.6 KB

  const int tid = threadIdx.x;
  const int r0 = blockIdx.x * 16;
  if (t0 > 0 && bs[t0] <= r0) return;      // retired in earlier chunk

  const int w  = tid >> 6;
  const int l  = tid & 63;
  const int lr = l & 15;
  const int lg = l >> 4;

  unsigned short* myb0 = &Ubuf[w][0][0];
  unsigned short* myb1 = &Ubuf[w][1][0];

  // stage phase-A unit u (kt=u>>1, half=u&1: half0=z ntiles, half1=r ntiles)
  auto STAGEA = [&](int u) {
    const unsigned short* src = UzrP + ((size_t)((u>>1)*64 + (u&1)*32 + w*4))*512 + l*8;
    unsigned short* dst = (u & 1) ? myb1 : myb0;
#pragma unroll
    for (int i = 0; i < 4; ++i) gload16(src + i*512, dst + i*512);
  };
  // stage phase-B unit u (kt=u)
  auto STAGEB = [&](int u) {
    const unsigned short* src = UhP + ((size_t)(u*32 + w*4))*512 + l*8;
    unsigned short* dst = (u & 1) ? myb1 : myb0;
#pragma unroll
    for (int i = 0; i < 4; ++i) gload16(src + i*512, dst + i*512);
  };

  // prologue: stage units A0, A1
  STAGEA(0); STAGEA(1);

  // load h master
  if (t0 == 0) {
    for (int i = tid; i < 16*512; i += 512) hm[i>>9][i&511] = 0.f;
  } else {
    for (int i = tid; i < 16*512; i += 512)
      hm[i>>9][i&511] = h_st[(size_t)(r0 + (i>>9))*HH + (i&511)];
  }

  for (int tc = 0; tc < TC; ++tc) {
    const int bsv = bs[t0 + tc];
    if (bsv <= r0) break;                  // descending bs: done forever
    const int na = min(16, bsv - r0);
    const unsigned short* PREstep = PRE + ((size_t)r0*TC + tc)*NN;

    barrier_lds();                         // S1: prev hm writes visible

    // hd build: hd[row][k] = (row<na ? gamma*h : h), frag layout -> hd_l
#pragma unroll
    for (int s2 = 0; s2 < 2; ++s2) {
      int s = tid + s2*512;
      int kt = s >> 6, ll = s & 63;
      int row = ll & 15, k0 = kt*32 + (ll >> 4)*8;
      bf16x8 gv = *(const bf16x8*)(PREstep + (size_t)row*TC*NN + 1536 + k0);
      bool act = row < na;
      unsigned short hv[8];
#pragma unroll
      for (int j = 0; j < 8; ++j) {
        float h = hm[row][k0 + j];
        hv[j] = f2bf(act ? bf2f((unsigned short)gv[j]) * h : h);
      }
      *(u16x4*)&hd_l[s*8]     = (u16x4){hv[0], hv[1], hv[2], hv[3]};
      *(u16x4*)&hd_l[s*8 + 4] = (u16x4){hv[4], hv[5], hv[6], hv[7]};
    }
    barrier_lds();                         // S2: hd_l ready

    // ---- phase A: z|r GEMM, pipelined units 0..31 ----
    f32x4 acc[8];
#pragma unroll
    for (int i = 0; i < 8; ++i) acc[i] = (f32x4){0.f, 0.f, 0.f, 0.f};
    bf16x8 af;
#pragma unroll
    for (int u = 0; u < 32; ++u) {
      asm volatile("s_waitcnt vmcnt(4)" ::: "memory");
      __builtin_amdgcn_sched_barrier(0);
      const unsigned short* buf = (u & 1) ? myb1 : myb0;
      if (!(u & 1)) af = *(const bf16x8*)&hd_l[((u>>1)*64 + l)*8];
#pragma unroll
      for (int i = 0; i < 4; ++i) {
        bf16x8 bf = *(const bf16x8*)&buf[i*512 + l*8];
        acc[(u&1)*4 + i] = __builtin_amdgcn_mfma_f32_16x16x32_bf16(af, bf, acc[(u&1)*4 + i], 0, 0, 0);
      }
      __builtin_amdgcn_sched_barrier(0);
      if (u < 30)       STAGEA(u + 2);
      else if (u == 30) STAGEB(0);
      else              STAGEB(1);
    }

    // phase A epilogue: z in regs (same wave/lane owns col in phase B), r -> rbuf
    float zreg[4][4];
#pragma unroll
    for (int i = 0; i < 4; ++i) {
      int col = (w*4 + i)*16 + lr;
#pragma unroll
      for (int q = 0; q < 4; ++q) {
        int row = lg*4 + q;
        const unsigned short* prow = PREstep + (size_t)row*TC*NN;
        float pz = bf2f(prow[col]);
        float pr = bf2f(prow[512 + col]);
        zreg[i][q] = 1.f/(1.f + __expf(-(pz + acc[i][q])));
        rbuf[row][col] = f2bf(1.f/(1.f + __expf(-(pr + acc[4+i][q]))));
      }
    }
    barrier_lds();                         // S3: rbuf ready, phase-A hd_l reads done

    // a2 = hd * r, in place in hd_l (same-thread same-slot)
#pragma unroll
    for (int s2 = 0; s2 < 2; ++s2) {
      int s = tid + s2*512;
      int kt = s >> 6, ll = s & 63;
      int row = ll & 15, k0 = kt*32 + (ll >> 4)*8;
#pragma unroll
      for (int j = 0; j < 8; ++j) {
        float a = bf2f(hd_l[s*8 + j]) * bf2f(rbuf[row][k0 + j]);
        hd_l[s*8 + j] = f2bf(a);
      }
    }
    barrier_lds();                         // S4: a2 frags ready

    // ---- phase B: htilde GEMM, pipelined units 0..15 ----
    f32x4 accB[4];
#pragma unroll
    for (int i = 0; i < 4; ++i) accB[i] = (f32x4){0.f, 0.f, 0.f, 0.f};
#pragma unroll
    for (int u = 0; u < 16; ++u) {
      asm volatile("s_waitcnt vmcnt(4)" ::: "memory");
      __builtin_amdgcn_sched_barrier(0);
      const unsigned short* buf = (u & 1) ? myb1 : myb0;
      bf16x8 af2 = *(const bf16x8*)&hd_l[(u*64 + l)*8];
#pragma unroll
      for (int i = 0; i < 4; ++i) {
        bf16x8 bf = *(const bf16x8*)&buf[i*512 + l*8];
        accB[i] = __builtin_amdgcn_mfma_f32_16x16x32_bf16(af2, bf, accB[i], 0, 0, 0);
      }
      __builtin_amdgcn_sched_barrier(0);
      if (u < 14)       STAGEB(u + 2);
      else if (u == 14) STAGEA(0);        // next step's pipeline head
      else              STAGEA(1);
    }

    // phase B epilogue: h update
#pragma unroll
    for (int i = 0; i < 4; ++i) {
      int col = (w*4 + i)*16 + lr;
#pragma unroll
      for (int q = 0; q < 4; ++q) {
        int row = lg*4 + q;
        if (row < na) {
          const unsigned short* prow = PREstep + (size_t)row*TC*NN;
          float ph = bf2f(prow[1024 + col]);
          float e  = __expf(2.f*(ph + accB[i][q]));
          float th = 1.f - 2.f/(e + 1.f);          // tanh, overflow-safe
          float g  = bf2f(prow[1536 + col]);
          float hd = g * hm[row][col];
          hm[row][col] = hd + zreg[i][q]*(th - hd);
        }
      }
    }
  }

  asm volatile("s_waitcnt vmcnt(0)" ::: "memory");  // drain stray prefetches
  barrier_lds();
  for (int i = tid; i < 16*512; i += 512)
    h_st[(size_t)(r0 + (i>>9))*HH + (i&511)] = hm[i>>9][i&511];
}

// ---------------------------------------------------------------------------
// K4: head: eval BatchNorm + decoder GEMV + log_softmax.
//   d_out = [output (256x64) | h_bn (256x512)] fp32
// ---------------------------------------------------------------------------
__global__ __launch_bounds__(64) void head_kernel(
    const float* __restrict__ h_state, const float* __restrict__ decW,
    const float* __restrict__ decb, const float* __restrict__ bnw,
    const float* __restrict__ bnb, float* __restrict__ out)
{
  int b = blockIdx.x, o = threadIdx.x;
  __shared__ float hbn[HH];
  const float s = rsqrtf(1.f + 1e-5f);
  for (int j = o; j < HH; j += 64)
    hbn[j] = h_state[(long)b*HH + j] * (bnw[j] * s) + bnb[j];
  __syncthreads();
  float acc = decb[o];
  for (int j = 0; j < HH; ++j) acc += hbn[j] * decW[j*OO + o];
  float mx = acc;
#pragma unroll
  for (int off = 32; off > 0; off >>= 1) mx = fmaxf(mx, __shfl_xor(mx, off));
  float ex = __expf(acc - mx);
  float sum = ex;
#pragma unroll
  for (int off = 32; off > 0; off >>= 1) sum += __shfl_xor(sum, off);
  out[(long)b*OO + o] = acc - mx - __logf(sum);
  for (int j = o; j < HH; j += 64)
    out[(long)BB*OO + (long)b*HH + j] = hbn[j];
}

// ---------------------------------------------------------------------------
extern "C" void kernel_launch(void* const* d_in, const int* in_sizes, int n_in,
                              void* d_out, int out_size, void* d_ws, size_t ws_size,
                              hipStream_t stream) {
  const float* x     = (const float*)d_in[0];
  const float* delta = (const float*)d_in[1];
  const float* mm    = (const float*)d_in[2];
  const float* xf    = (const float*)d_in[3];
  const int*   bs    = (const int*)  d_in[4];
  const float* W_r   = (const float*)d_in[5];
  const float* U_r   = (const float*)d_in[6];
  const float* V_r   = (const float*)d_in[7];
  const float* b_r   = (const float*)d_in[8];
  const float* W_z   = (const float*)d_in[9];
  const float* U_z   = (const float*)d_in[10];
  const float* V_z   = (const float*)d_in[11];
  const float* b_z   = (const float*)d_in[12];
  const float* W     = (const float*)d_in[13];
  const float* U     = (const float*)d_in[14];
  const float* V     = (const float*)d_in[15];
  const float* b     = (const float*)d_in[16];
  const float* Wgx   = (const float*)d_in[17];
  const float* bgx   = (const float*)d_in[18];
  const float* Wgh   = (const float*)d_in[19];
  const float* bgh   = (const float*)d_in[20];
  const float* decW  = (const float*)d_in[21];
  const float* decb  = (const float*)d_in[22];
  const float* bnw   = (const float*)d_in[23];
  const float* bnb   = (const float*)d_in[24];

  auto rnd = [](size_t v) { return (v + 255) & ~(size_t)255; };
  const size_t fixed_bytes = rnd((size_t)2048*256*2) + rnd(2048*4)
                           + rnd((size_t)16*64*64*8*2) + rnd((size_t)16*32*64*8*2)
                           + rnd((size_t)BB*HH*4);
  int TC = 0;
  const int cands[5] = {128, 64, 32, 16, 8};
  for (int i = 0; i < 5; ++i) {
    size_t need = fixed_bytes + rnd((size_t)BB*cands[i]*KK*2) + rnd((size_t)BB*cands[i]*NN*2);
    if (need <= ws_size) { TC = cands[i]; break; }
  }
  if (TC == 0) return;

  char* p = (char*)d_ws;
  auto alloc = [&](size_t bytes) { char* r = p; p += (bytes + 255) & ~(size_t)255; return r; };
  unsigned short* A_chunk = (unsigned short*)alloc((size_t)BB * TC * KK * 2);
  unsigned short* PREc    = (unsigned short*)alloc((size_t)BB * TC * NN * 2);
  unsigned short* BwT     = (unsigned short*)alloc((size_t)2048 * 256 * 2);
  float*          bias    = (float*)alloc(2048 * 4);
  unsigned short* UzrP    = (unsigned short*)alloc((size_t)16*64*64*8 * 2);
  unsigned short* UhP     = (unsigned short*)alloc((size_t)16*32*64*8 * 2);
  float*          h_st    = (float*)alloc((size_t)BB * HH * 4);

  prep_kernel<<<5128, 256, 0, stream>>>(W_z, V_z, b_z, W_r, V_r, b_r, W, V, b,
                                        Wgh, bgh, U_z, U_r, U, BwT, bias, UzrP, UhP);
  const int nch = TT / TC;
  for (int c = 0; c < nch; ++c) {
    int t0 = c * TC;
    build_A_kernel<<<BB*TC/8, 256, 0, stream>>>(x, delta, mm, xf, Wgx, bgx, bs,
                                                A_chunk, t0, TC);
    gemm1_kernel<<<(BB*TC/128)*16, 256, 0, stream>>>(A_chunk, BwT, bias, bs,
                                                     PREc, t0, TC);
    scan_kernel<<<16, 512, 0, stream>>>(PREc, UzrP, UhP, bs, h_st, t0, TC);
  }
  head_kernel<<<256, 64, 0, stream>>>(h_st, decW, decb, bnw, bnb, (float*)d_out);
}